// Round 3
// baseline (69.230 us; speedup 1.0000x reference)
//
#include <hip/hip_runtime.h>
#include <hip/hip_bf16.h>
#include <math.h>

// Problem sizes (fixed by setup_inputs): B=4096, D=128, K=256, c=1.0
#define B_SZ 4096
#define D_SZ 128
#define K_SZ 256
#define MIN_NORM 1e-15f

typedef __attribute__((ext_vector_type(8))) short  short8;   // MFMA A/B frag (8 bf16)
typedef __attribute__((ext_vector_type(4))) float  floatx4;  // MFMA C/D frag

// 8 f32 -> 8 bf16 (RNE) via packed v_cvt_pk_bf16_f32
static __device__ __forceinline__ short8 cvt8(float4 a, float4 b) {
    union { short8 s; __hip_bfloat162 h[4]; } u;
    u.h[0] = __float22bfloat162_rn(make_float2(a.x, a.y));
    u.h[1] = __float22bfloat162_rn(make_float2(a.z, a.w));
    u.h[2] = __float22bfloat162_rn(make_float2(b.x, b.y));
    u.h[3] = __float22bfloat162_rn(make_float2(b.z, b.w));
    return u.s;
}
static __device__ __forceinline__ float dot4(float4 a, float4 b) {
    return a.x * b.x + a.y * b.y + a.z * b.z + a.w * b.w;
}

// One wave = one 16x16 output tile. No LDS, no __syncthreads.
// A/B fragments loaded straight from global (f32) and packed to bf16 in-register;
// all stats computed from the same f32 values + shfl reductions.
__global__ __launch_bounds__(256) void mobius_mlr_kernel(
        const float* __restrict__ x, const float* __restrict__ p,
        const float* __restrict__ a, float* __restrict__ out) {
    const int tid  = threadIdx.x;
    const int lane = tid & 63;
    const int wv   = tid >> 6;
    const int w    = blockIdx.x * 4 + wv;   // 0..4095 global wave id
    const int ct   = w & 15;                // col tile (k prototypes), 16 tiles
    const int rt   = w >> 4;                // row tile (batch), 256 tiles
    const int r16  = lane & 15;
    const int quad = lane >> 4;

    // MFMA 16x16x32 frag layout: lane holds row (lane&15), k = quad*8 + j
    const float* xrow = x + (size_t)(rt * 16 + r16) * D_SZ;
    const float* prow = p + (size_t)(ct * 16 + r16) * D_SZ;
    const float* arow = a + (size_t)(ct * 16 + r16) * D_SZ;

    floatx4 accp = {0.f, 0.f, 0.f, 0.f};
    floatx4 acca = {0.f, 0.f, 0.f, 0.f};
    float x2 = 0.f, p2 = 0.f, pa = 0.f, a2 = 0.f;

    #pragma unroll
    for (int dc = 0; dc < 4; ++dc) {
        const int d0 = dc * 32 + quad * 8;
        float4 xv0 = *(const float4*)(xrow + d0);
        float4 xv1 = *(const float4*)(xrow + d0 + 4);
        float4 pv0 = *(const float4*)(prow + d0);
        float4 pv1 = *(const float4*)(prow + d0 + 4);
        float4 av0 = *(const float4*)(arow + d0);
        float4 av1 = *(const float4*)(arow + d0 + 4);

        // f32 stats on this lane's k-chunk
        x2 += dot4(xv0, xv0) + dot4(xv1, xv1);
        p2 += dot4(pv0, pv0) + dot4(pv1, pv1);
        pa += dot4(pv0, av0) + dot4(pv1, av1);
        a2 += dot4(av0, av0) + dot4(av1, av1);

        short8 af = cvt8(xv0, xv1);
        short8 bp = cvt8(pv0, pv1);
        short8 ba = cvt8(av0, av1);
        accp = __builtin_amdgcn_mfma_f32_16x16x32_bf16(af, bp, accp, 0, 0, 0);
        acca = __builtin_amdgcn_mfma_f32_16x16x32_bf16(af, ba, acca, 0, 0, 0);
    }

    // Reduce stats across the 4 quads (disjoint k-chunks of the same row/col).
    // After xor-16/32, every lane has the full sum for its row index (lane&15).
    x2 += __shfl_xor(x2, 16); x2 += __shfl_xor(x2, 32);
    p2 += __shfl_xor(p2, 16); p2 += __shfl_xor(p2, 32);
    pa += __shfl_xor(pa, 16); pa += __shfl_xor(pa, 32);
    a2 += __shfl_xor(a2, 16); a2 += __shfl_xor(a2, 32);
    const float an = fmaxf(sqrtf(a2), MIN_NORM);   // per output col (lane&15) ✓ aligned

    // C/D layout (verified): col = lane&15, row = quad*4 + reg
    const int colg = ct * 16 + r16;
    #pragma unroll
    for (int r = 0; r < 4; ++r) {
        const int rowl = quad * 4 + r;
        const float x2v = __shfl(x2, rowl);        // row-stat lives in lane `rowl`
        const float pdx = accp[r];                 // p_k . x_b   (bf16 MFMA)
        const float xda = acca[r];                 // x_b . a_k
        // mobius_add(-p, x, c=1): xy = -(p.x), x2 = |p|^2, y2 = |x|^2
        const float alpha = 1.0f - 2.0f * pdx + x2v;
        const float beta  = 1.0f - p2;
        const float den   = fmaxf(1.0f - 2.0f * pdx + p2 * x2v, MIN_NORM);
        const float invd  = __builtin_amdgcn_rcpf(den);
        float sqn = (alpha * alpha * p2 - 2.0f * alpha * beta * pdx
                     + beta * beta * x2v) * invd * invd;       // |mpx|^2
        sqn = fmaxf(sqn, MIN_NORM);
        const float mda  = (beta * xda - alpha * pa) * invd;   // mpx . a
        const float dden = fmaxf((1.0f - sqn) * an, MIN_NORM);
        const float z    = 2.0f * mda * __builtin_amdgcn_rcpf(dden);
        const float dist = __logf(z + sqrtf(z * z + 1.0f));    // asinh(z), z ~ O(0.02)
        out[(size_t)(rt * 16 + rowl) * K_SZ + colg] = 2.0f * an * dist;
    }
}

extern "C" void kernel_launch(void* const* d_in, const int* in_sizes, int n_in,
                              void* d_out, int out_size, void* d_ws, size_t ws_size,
                              hipStream_t stream) {
    const float* x = (const float*)d_in[0];
    const float* p = (const float*)d_in[1];
    const float* a = (const float*)d_in[2];
    float* out = (float*)d_out;
    // 4096 waves (one per 16x16 tile) = 1024 blocks x 4 waves -> 4 blocks/CU
    mobius_mlr_kernel<<<dim3(1024), dim3(256), 0, stream>>>(x, p, a, out);
}

// Round 4
// 63.699 us; speedup vs baseline: 1.0868x; 1.0868x over previous
//
#include <hip/hip_runtime.h>
#include <hip/hip_bf16.h>
#include <math.h>

// Problem sizes (fixed by setup_inputs): B=4096, D=128, K=256, c=1.0
#define B_SZ 4096
#define D_SZ 128
#define K_SZ 256
#define MT   32          // m-tile (batch rows) per block
#define NT   32          // n-tile (k prototypes) per block
#define LSTR 136         // LDS row stride in bf16 elems (272B, 16B-aligned rows)
#define MIN_NORM 1e-15f

typedef __attribute__((ext_vector_type(8))) short  short8;   // MFMA A/B frag (8 bf16)
typedef __attribute__((ext_vector_type(4))) float  floatx4;  // MFMA C/D frag

// 4 f32 -> 4 bf16 (RNE) via packed v_cvt_pk_bf16_f32
static __device__ __forceinline__ ushort4 cvt4(float4 a) {
    union { ushort4 s; __hip_bfloat162 h[2]; } u;
    u.h[0] = __float22bfloat162_rn(make_float2(a.x, a.y));
    u.h[1] = __float22bfloat162_rn(make_float2(a.z, a.w));
    return u.s;
}
static __device__ __forceinline__ float dot4(float4 a, float4 b) {
    return a.x * b.x + a.y * b.y + a.z * b.z + a.w * b.w;
}

// 32x32 output tile per block; coalesced f32 staging -> bf16 LDS; stats
// computed in f32 from the staged values during the load pass (no second
// LDS read pass); ONE __syncthreads total; 4 waves x 8 MFMA; fused epilogue.
__global__ __launch_bounds__(256) void mobius_mlr_kernel(
        const float* __restrict__ x, const float* __restrict__ p,
        const float* __restrict__ a, float* __restrict__ out) {
    // 3 x (32 x 136 x 2B) = 26112 B tile LDS + stat arrays
    __shared__ __align__(16) unsigned short lx[MT * LSTR];
    __shared__ __align__(16) unsigned short lp[NT * LSTR];
    __shared__ __align__(16) unsigned short la[NT * LSTR];
    __shared__ float xsq[MT];                   // |x_b|^2
    __shared__ float p2s[NT], pas[NT], ans[NT]; // |p|^2, p.a, max(||a||,MIN_NORM)

    const int tid = threadIdx.x;
    const int mb0 = blockIdx.x * MT;
    const int nb0 = blockIdx.y * NT;

    // ---- staging + stats in one pass: 8 threads per row, 64B (4xfloat4) each ----
    const int row = tid >> 3;        // 0..31
    const int seg = tid & 7;         // 0..7 -> 16-float segment
    const float* xrow = x + (size_t)(mb0 + row) * D_SZ + seg * 16;
    const float* prow = p + (size_t)(nb0 + row) * D_SZ + seg * 16;
    const float* arow = a + (size_t)(nb0 + row) * D_SZ + seg * 16;

    float4 xv[4], pv[4], av[4];
    #pragma unroll
    for (int i = 0; i < 4; ++i) xv[i] = *(const float4*)(xrow + i * 4);
    #pragma unroll
    for (int i = 0; i < 4; ++i) pv[i] = *(const float4*)(prow + i * 4);
    #pragma unroll
    for (int i = 0; i < 4; ++i) av[i] = *(const float4*)(arow + i * 4);

    float x2 = 0.f, p2 = 0.f, pa = 0.f, a2 = 0.f;
    #pragma unroll
    for (int i = 0; i < 4; ++i) {
        x2 += dot4(xv[i], xv[i]);
        p2 += dot4(pv[i], pv[i]);
        pa += dot4(pv[i], av[i]);
        a2 += dot4(av[i], av[i]);
        *(ushort4*)&lx[row * LSTR + seg * 16 + i * 4] = cvt4(xv[i]);
        *(ushort4*)&lp[row * LSTR + seg * 16 + i * 4] = cvt4(pv[i]);
        *(ushort4*)&la[row * LSTR + seg * 16 + i * 4] = cvt4(av[i]);
    }
    // reduce across the 8 segment-lanes of this row (same wave: xor < 8)
    x2 += __shfl_xor(x2, 1); x2 += __shfl_xor(x2, 2); x2 += __shfl_xor(x2, 4);
    p2 += __shfl_xor(p2, 1); p2 += __shfl_xor(p2, 2); p2 += __shfl_xor(p2, 4);
    pa += __shfl_xor(pa, 1); pa += __shfl_xor(pa, 2); pa += __shfl_xor(pa, 4);
    a2 += __shfl_xor(a2, 1); a2 += __shfl_xor(a2, 2); a2 += __shfl_xor(a2, 4);
    if (seg == 0) {
        xsq[row] = x2;
        p2s[row] = p2;
        pas[row] = pa;
        ans[row] = fmaxf(sqrtf(a2), MIN_NORM);
    }
    __syncthreads();   // the ONLY barrier

    // ---- MFMA: each wave computes one 16x16 quadrant of both GEMMs ----
    const int lane = tid & 63;
    const int wv   = tid >> 6;
    const int mi   = wv & 1;            // m-quadrant
    const int ni   = wv >> 1;           // n-quadrant
    const int quad = lane >> 4;
    const int r16  = lane & 15;

    floatx4 accp = {0.f, 0.f, 0.f, 0.f};
    floatx4 acca = {0.f, 0.f, 0.f, 0.f};
    #pragma unroll
    for (int dc = 0; dc < 4; ++dc) {
        int d0 = dc * 32 + quad * 8;
        short8 af = *(const short8*)&lx[(mi * 16 + r16) * LSTR + d0];
        short8 bp = *(const short8*)&lp[(ni * 16 + r16) * LSTR + d0];
        short8 ba = *(const short8*)&la[(ni * 16 + r16) * LSTR + d0];
        accp = __builtin_amdgcn_mfma_f32_16x16x32_bf16(af, bp, accp, 0, 0, 0);
        acca = __builtin_amdgcn_mfma_f32_16x16x32_bf16(af, ba, acca, 0, 0, 0);
    }

    // ---- fused epilogue ----
    // C/D layout (verified): col = lane&15, row = (lane>>4)*4 + reg
    const int coll = ni * 16 + r16;
    const float p2v = p2s[coll];
    const float pav = pas[coll];
    const float anv = ans[coll];
    #pragma unroll
    for (int r = 0; r < 4; ++r) {
        int rowl = mi * 16 + quad * 4 + r;
        float x2v = xsq[rowl];
        float pdx = accp[r];        // p_k . x_b   (bf16 MFMA)
        float xda = acca[r];        // x_b . a_k
        // mobius_add(-p, x, c=1): xy = -(p.x), x2 = |p|^2, y2 = |x|^2
        float alpha = 1.0f - 2.0f * pdx + x2v;
        float beta  = 1.0f - p2v;
        float den   = fmaxf(1.0f - 2.0f * pdx + p2v * x2v, MIN_NORM);
        float invd  = __builtin_amdgcn_rcpf(den);
        float sqn   = (alpha * alpha * p2v - 2.0f * alpha * beta * pdx
                       + beta * beta * x2v) * invd * invd;   // |mpx|^2
        sqn = fmaxf(sqn, MIN_NORM);
        float mda  = (beta * xda - alpha * pav) * invd;      // mpx . a
        float dden = fmaxf((1.0f - sqn) * anv, MIN_NORM);
        float z    = 2.0f * mda * __builtin_amdgcn_rcpf(dden);
        float dist = __logf(z + sqrtf(z * z + 1.0f));        // asinh(z), z ~ O(0.02)
        out[(size_t)(mb0 + rowl) * K_SZ + (nb0 + coll)] = 2.0f * anv * dist;
    }
}

extern "C" void kernel_launch(void* const* d_in, const int* in_sizes, int n_in,
                              void* d_out, int out_size, void* d_ws, size_t ws_size,
                              hipStream_t stream) {
    const float* x = (const float*)d_in[0];
    const float* p = (const float*)d_in[1];
    const float* a = (const float*)d_in[2];
    float* out = (float*)d_out;
    dim3 grid(B_SZ / MT, K_SZ / NT);   // (128, 8) = 1024 blocks -> 4 blocks/CU
    mobius_mlr_kernel<<<grid, dim3(256), 0, stream>>>(x, p, a, out);
}